// Round 1
// baseline (145.872 us; speedup 1.0000x reference)
//
#include <hip/hip_runtime.h>

#define D 1024
#define TWO_D 2048
#define NB 8
#define T 4096
#define KCHUNKS 16
#define KCHUNK 128

// ---------------- leaves: partial sums over t-chunks of 32 ----------------
__global__ void __launch_bounds__(256) leaves_partial(const float* __restrict__ x,
                                                      float* __restrict__ lpart) {
    int b = blockIdx.x, leaf = blockIdx.y, tc = blockIdx.z;
    int tid = threadIdx.x;
    const float4* xp = (const float4*)x;
    size_t base = ((size_t)b * T + (size_t)leaf * 256 + (size_t)tc * 32) * (D / 4) + tid;
    float4 acc = {0.f, 0.f, 0.f, 0.f};
#pragma unroll 8
    for (int tt = 0; tt < 32; ++tt) {
        float4 v = xp[base + (size_t)tt * (D / 4)];
        acc.x += v.x; acc.y += v.y; acc.z += v.z; acc.w += v.w;
    }
    ((float4*)lpart)[(((b * 8 + leaf) * 8 + tc) * (D / 4)) + tid] = acc;
}

// ---------------- leaves: reduce 8 partials -> used[b][leaf][d] (mean) ----
__global__ void __launch_bounds__(256) leaves_reduce(const float* __restrict__ lpart,
                                                     float* __restrict__ used) {
    int gid = blockIdx.x * 256 + threadIdx.x;   // over 8*8*(D/4) = 16384
    int bl = gid / (D / 4);
    int c = gid % (D / 4);
    const float4* lp = (const float4*)lpart;
    float4 acc = {0.f, 0.f, 0.f, 0.f};
#pragma unroll
    for (int tc = 0; tc < 8; ++tc) {
        float4 v = lp[(bl * 8 + tc) * (D / 4) + c];
        acc.x += v.x; acc.y += v.y; acc.z += v.z; acc.w += v.w;
    }
    const float s = 1.0f / 256.0f;
    acc.x *= s; acc.y *= s; acc.z *= s; acc.w *= s;
    ((float4*)used)[gid] = acc;
}

// ---------------- per-level skinny GEMM, K-split partials ----------------
// proj_partial[node][kc][b][col] = sum_{k in chunk} fused[b][node][k] * W[node_base+node][k][col]
__global__ void __launch_bounds__(256) tree_gemm_partial(const float* __restrict__ in_states,
                                                         const float* __restrict__ W,
                                                         float* __restrict__ gpart,
                                                         int node_base, int nin, int pair) {
    int node = blockIdx.x;
    int c0 = blockIdx.y * 256;
    int k0 = blockIdx.z * KCHUNK;
    int tid = threadIdx.x;

    __shared__ float fs[KCHUNK][8];
    for (int idx = tid; idx < KCHUNK * 8; idx += 256) {
        int kk = idx >> 3, b = idx & 7;
        int k = k0 + kk;
        int src = pair ? (2 * node + (k >> 10)) : node;
        fs[kk][b] = in_states[(size_t)b * nin * D + (size_t)src * D + (k & 1023)];
    }
    __syncthreads();

    int col = c0 + tid;
    const float* Wp = W + (size_t)(node_base + node) * TWO_D * D + (size_t)k0 * D + col;
    float acc0 = 0.f, acc1 = 0.f, acc2 = 0.f, acc3 = 0.f;
    float acc4 = 0.f, acc5 = 0.f, acc6 = 0.f, acc7 = 0.f;
#pragma unroll 8
    for (int kk = 0; kk < KCHUNK; ++kk) {
        float w = Wp[(size_t)kk * D];
        float4 f0 = *(const float4*)&fs[kk][0];
        float4 f1 = *(const float4*)&fs[kk][4];
        acc0 += f0.x * w; acc1 += f0.y * w; acc2 += f0.z * w; acc3 += f0.w * w;
        acc4 += f1.x * w; acc5 += f1.y * w; acc6 += f1.z * w; acc7 += f1.w * w;
    }
    size_t gb = ((size_t)(node * KCHUNKS + blockIdx.z) * 8) * D + col;
    gpart[gb + 0 * D] = acc0; gpart[gb + 1 * D] = acc1;
    gpart[gb + 2 * D] = acc2; gpart[gb + 3 * D] = acc3;
    gpart[gb + 4 * D] = acc4; gpart[gb + 5 * D] = acc5;
    gpart[gb + 6 * D] = acc6; gpart[gb + 7 * D] = acc7;
}

// ---------------- per-level: reduce partials, add bias, spike gate --------
__global__ void __launch_bounds__(256) tree_gate_reduce(const float* __restrict__ gpart,
                                                        const float* __restrict__ bias,
                                                        const float* __restrict__ bt,
                                                        float* __restrict__ out_states,
                                                        int node_base, int size) {
    int gid = blockIdx.x * 256 + threadIdx.x;   // over size*8*1024
    int col = gid & 1023;
    int b = (gid >> 10) & 7;
    int node = gid >> 13;
    float p = bias[(size_t)(node_base + node) * D + col];
#pragma unroll
    for (int kc = 0; kc < KCHUNKS; ++kc)
        p += gpart[(((size_t)node * KCHUNKS + kc) * 8 + b) * D + col];
    float u = p - bt[(size_t)(node_base + node) * D + col];
    out_states[((size_t)b * size + node) * D + col] = (u > 0.0f) ? p : 0.0f;
}

// ---------------- final: out = layernorm(root[b] + x[b,t]) ----------------
__global__ void __launch_bounds__(256) add_ln(const float* __restrict__ x,
                                              const float* __restrict__ root,
                                              const float* __restrict__ lw,
                                              const float* __restrict__ lb,
                                              float* __restrict__ out) {
    int row = blockIdx.x;          // b*T + t
    int b = row >> 12;
    int tid = threadIdx.x;
    const float4* xr = (const float4*)x + (size_t)row * (D / 4);
    float4 r = ((const float4*)root)[b * (D / 4) + tid];
    float4 v = xr[tid];
    v.x += r.x; v.y += r.y; v.z += r.z; v.w += r.w;

    float s = v.x + v.y + v.z + v.w;
    float q = v.x * v.x + v.y * v.y + v.z * v.z + v.w * v.w;
#pragma unroll
    for (int off = 32; off; off >>= 1) {
        s += __shfl_down(s, off);
        q += __shfl_down(q, off);
    }
    __shared__ float ss[4], sq[4];
    int wave = tid >> 6, lane = tid & 63;
    if (lane == 0) { ss[wave] = s; sq[wave] = q; }
    __syncthreads();
    s = ss[0] + ss[1] + ss[2] + ss[3];
    q = sq[0] + sq[1] + sq[2] + sq[3];

    float mean = s * (1.0f / D);
    float var = q * (1.0f / D) - mean * mean;
    float rstd = rsqrtf(var + 1e-5f);

    float4 w4 = ((const float4*)lw)[tid];
    float4 b4 = ((const float4*)lb)[tid];
    float4 o;
    o.x = (v.x - mean) * rstd * w4.x + b4.x;
    o.y = (v.y - mean) * rstd * w4.y + b4.y;
    o.z = (v.z - mean) * rstd * w4.z + b4.z;
    o.w = (v.w - mean) * rstd * w4.w + b4.w;
    ((float4*)out)[(size_t)row * (D / 4) + tid] = o;
}

extern "C" void kernel_launch(void* const* d_in, const int* in_sizes, int n_in,
                              void* d_out, int out_size, void* d_ws, size_t ws_size,
                              hipStream_t stream) {
    const float* x    = (const float*)d_in[0];
    const float* W    = (const float*)d_in[1];
    const float* bias = (const float*)d_in[2];
    const float* bt   = (const float*)d_in[3];
    const float* lw   = (const float*)d_in[4];
    const float* lb   = (const float*)d_in[5];
    float* out = (float*)d_out;

    float* ws    = (float*)d_ws;
    float* lpart = ws;                  // 8*8*8*1024   = 524288 floats
    float* used  = lpart + 524288;      // 8*8*1024     = 65536
    float* stA   = used + 65536;        // 8*8*1024
    float* stB   = stA + 65536;         // 8*8*1024
    float* gpart = stB + 65536;         // 8*16*8*1024  = 1048576

    // 1) leaf means (only first 8 leaves are ever used)
    leaves_partial<<<dim3(8, 8, 8), 256, 0, stream>>>(x, lpart);
    leaves_reduce<<<64, 256, 0, stream>>>(lpart, used);

    // 2) tree levels: {base, size, nin, pair, in, out}
    struct Lv { int base, size, nin, pair; const float* in; float* outp; };
    Lv lv[4] = {
        {7, 8, 8, 0, used, stA},
        {3, 4, 8, 1, stA,  stB},
        {1, 2, 4, 1, stB,  stA},
        {0, 1, 2, 1, stA,  stB},
    };
    for (int i = 0; i < 4; ++i) {
        tree_gemm_partial<<<dim3(lv[i].size, 4, KCHUNKS), 256, 0, stream>>>(
            lv[i].in, W, gpart, lv[i].base, lv[i].nin, lv[i].pair);
        tree_gate_reduce<<<lv[i].size * 32, 256, 0, stream>>>(
            gpart, bias, bt, lv[i].outp, lv[i].base, lv[i].size);
    }

    // 3) out = layernorm(root + x); root is stB[b][0][:]
    add_ln<<<NB * T, 256, 0, stream>>>(x, stB, lw, lb, out);
}

// Round 3
// 123.143 us; speedup vs baseline: 1.1846x; 1.1846x over previous
//
#include <hip/hip_runtime.h>

#define D 1024
#define NB 8
#define T 4096

typedef float fvec4 __attribute__((ext_vector_type(4)));

// ---------------- leaves: partial sums over t-chunks of 32 ----------------
// lpart[b][leaf][tc][col] = sum of 32 rows
__global__ void __launch_bounds__(256) leaves_partial(const float* __restrict__ x,
                                                      float* __restrict__ lpart) {
    int b = blockIdx.x, leaf = blockIdx.y, tc = blockIdx.z;
    int tid = threadIdx.x;
    const float4* xp = (const float4*)x;
    size_t base = ((size_t)b * T + (size_t)leaf * 256 + (size_t)tc * 32) * (D / 4) + tid;
    float4 acc = {0.f, 0.f, 0.f, 0.f};
#pragma unroll 8
    for (int tt = 0; tt < 32; ++tt) {
        float4 v = xp[base + (size_t)tt * (D / 4)];
        acc.x += v.x; acc.y += v.y; acc.z += v.z; acc.w += v.w;
    }
    ((float4*)lpart)[(((b * 8 + leaf) * 8 + tc) * (D / 4)) + tid] = acc;
}

// ---------------- fused tree-level GEMM -----------------------------------
// MODE 0: inputs are lpart partials (leaf level) -> average on the fly.
// MODE 1: inputs are previous level's K-split partials -> reduce+bias+gate
//         on the fly while staging into LDS.
// Output: gout[node][kc][b][col] partial sums (K-split by gridDim.z).
template <int KCH, int KCPREV, int MODE>
__global__ void __launch_bounds__(256) tree_gemm(const float* __restrict__ gprev,
                                                 const float* __restrict__ W,
                                                 const float* __restrict__ bias,
                                                 const float* __restrict__ bt,
                                                 float* __restrict__ gout,
                                                 int node_base, int prev_base) {
    int node = blockIdx.x;
    int c0 = blockIdx.y * 256;
    int k0 = blockIdx.z * KCH;
    int tid = threadIdx.x;
    int nkc = gridDim.z;

    __shared__ float fs[KCH][8];
    for (int idx = tid; idx < KCH * 8; idx += 256) {
        int kk = idx % KCH;          // kk fastest -> coalesced gate-sum reads
        int b = idx / KCH;
        int k = k0 + kk;
        int col = k & 1023;
        float v;
        if (MODE == 0) {
            float p = 0.f;
#pragma unroll
            for (int tc = 0; tc < 8; ++tc)
                p += gprev[(((size_t)(b * 8 + node)) * 8 + tc) * D + col];
            v = p * (1.0f / 256.0f);
        } else {
            int src = 2 * node + (k >> 10);
            float p = bias[(size_t)(prev_base + src) * D + col];
#pragma unroll
            for (int kc = 0; kc < KCPREV; ++kc)
                p += gprev[(((size_t)src * KCPREV + kc) * 8 + b) * D + col];
            float u = p - bt[(size_t)(prev_base + src) * D + col];
            v = (u > 0.0f) ? p : 0.0f;
        }
        fs[kk][b] = v;
    }
    __syncthreads();

    int col = c0 + tid;
    const float* Wp = W + (size_t)(node_base + node) * 2048 * D + (size_t)k0 * D + col;
    float acc0 = 0.f, acc1 = 0.f, acc2 = 0.f, acc3 = 0.f;
    float acc4 = 0.f, acc5 = 0.f, acc6 = 0.f, acc7 = 0.f;
#pragma unroll 8
    for (int kk = 0; kk < KCH; ++kk) {
        float w = Wp[(size_t)kk * D];
        float4 f0 = *(const float4*)&fs[kk][0];   // broadcast, conflict-free
        float4 f1 = *(const float4*)&fs[kk][4];
        acc0 += f0.x * w; acc1 += f0.y * w; acc2 += f0.z * w; acc3 += f0.w * w;
        acc4 += f1.x * w; acc5 += f1.y * w; acc6 += f1.z * w; acc7 += f1.w * w;
    }
    size_t gb = ((size_t)(node * nkc + blockIdx.z) * 8) * D + col;
    gout[gb + 0 * D] = acc0; gout[gb + 1 * D] = acc1;
    gout[gb + 2 * D] = acc2; gout[gb + 3 * D] = acc3;
    gout[gb + 4 * D] = acc4; gout[gb + 5 * D] = acc5;
    gout[gb + 6 * D] = acc6; gout[gb + 7 * D] = acc7;
}

// ---------------- root: reduce level-0 partials, bias, gate ---------------
template <int KC>
__global__ void __launch_bounds__(256) root_gate(const float* __restrict__ gpart,
                                                 const float* __restrict__ bias,
                                                 const float* __restrict__ bt,
                                                 float* __restrict__ root) {
    int gid = blockIdx.x * 256 + threadIdx.x;   // over 8*1024
    int col = gid & 1023;
    int b = gid >> 10;
    float p = bias[col];                        // node 0
#pragma unroll
    for (int kc = 0; kc < KC; ++kc)
        p += gpart[((size_t)kc * 8 + b) * D + col];
    float u = p - bt[col];
    root[gid] = (u > 0.0f) ? p : 0.0f;
}

// ---------------- final: out = layernorm(root[b] + x[b,t]) ----------------
__global__ void __launch_bounds__(256) add_ln(const float* __restrict__ x,
                                              const float* __restrict__ root,
                                              const float* __restrict__ lw,
                                              const float* __restrict__ lb,
                                              float* __restrict__ out) {
    int row = blockIdx.x;          // b*T + t
    int b = row >> 12;
    int tid = threadIdx.x;
    const fvec4* xr = (const fvec4*)x + (size_t)row * (D / 4);
    float4 r = ((const float4*)root)[b * (D / 4) + tid];
    fvec4 vv = __builtin_nontemporal_load(xr + tid);
    float4 v;
    v.x = vv.x + r.x; v.y = vv.y + r.y; v.z = vv.z + r.z; v.w = vv.w + r.w;

    float s = v.x + v.y + v.z + v.w;
    float q = v.x * v.x + v.y * v.y + v.z * v.z + v.w * v.w;
#pragma unroll
    for (int off = 32; off; off >>= 1) {
        s += __shfl_down(s, off);
        q += __shfl_down(q, off);
    }
    __shared__ float ss[4], sq[4];
    int wave = tid >> 6, lane = tid & 63;
    if (lane == 0) { ss[wave] = s; sq[wave] = q; }
    __syncthreads();
    s = ss[0] + ss[1] + ss[2] + ss[3];
    q = sq[0] + sq[1] + sq[2] + sq[3];

    float mean = s * (1.0f / D);
    float var = q * (1.0f / D) - mean * mean;
    float rstd = rsqrtf(var + 1e-5f);

    float4 w4 = ((const float4*)lw)[tid];
    float4 b4 = ((const float4*)lb)[tid];
    fvec4 o;
    o.x = (v.x - mean) * rstd * w4.x + b4.x;
    o.y = (v.y - mean) * rstd * w4.y + b4.y;
    o.z = (v.z - mean) * rstd * w4.z + b4.z;
    o.w = (v.w - mean) * rstd * w4.w + b4.w;
    __builtin_nontemporal_store(o, (fvec4*)out + (size_t)row * (D / 4) + tid);
}

extern "C" void kernel_launch(void* const* d_in, const int* in_sizes, int n_in,
                              void* d_out, int out_size, void* d_ws, size_t ws_size,
                              hipStream_t stream) {
    const float* x    = (const float*)d_in[0];
    const float* W    = (const float*)d_in[1];
    const float* bias = (const float*)d_in[2];
    const float* bt   = (const float*)d_in[3];
    const float* lw   = (const float*)d_in[4];
    const float* lb   = (const float*)d_in[5];
    float* out = (float*)d_out;

    float* ws    = (float*)d_ws;
    float* lpart = ws;                   // 8*8*8*1024      = 524288 floats
    float* gA    = lpart + 524288;       // up to 128*8*1024 = 1048576
    float* gB    = gA + 1048576;         // up to 64*8*1024  = 524288
    float* root  = gB + 524288;          // 8*1024

    // 1) leaf partial means (only first 8 leaves are ever used)
    leaves_partial<<<dim3(8, 8, 8), 256, 0, stream>>>(x, lpart);

    // 2) tree levels, gate fused into consumer staging
    // leaf level (nodes 7..14): avg(lpart) -> gA (16 k-chunks)
    tree_gemm<128, 8, 0><<<dim3(8, 4, 16), 256, 0, stream>>>(
        lpart, W, bias, bt, gA, 7, 0);
    // level 2 (nodes 3..6): gate(gA,base 7) -> gB (16 k-chunks)
    tree_gemm<128, 16, 1><<<dim3(4, 4, 16), 256, 0, stream>>>(
        gA, W, bias, bt, gB, 3, 7);
    // level 1 (nodes 1..2): gate(gB,base 3) -> gA (32 k-chunks)
    tree_gemm<64, 16, 1><<<dim3(2, 4, 32), 256, 0, stream>>>(
        gB, W, bias, bt, gA, 1, 3);
    // level 0 (node 0): gate(gA,base 1) -> gB (64 k-chunks)
    tree_gemm<32, 32, 1><<<dim3(1, 4, 64), 256, 0, stream>>>(
        gA, W, bias, bt, gB, 0, 1);

    // 3) root = gate(bias0 + sum gB, bt0)
    root_gate<64><<<32, 256, 0, stream>>>(gB, bias, bt, root);

    // 4) out = layernorm(root + x)
    add_ln<<<NB * T, 256, 0, stream>>>(x, root, lw, lb, out);
}